// Round 3
// baseline (418.491 us; speedup 1.0000x reference)
//
#include <hip/hip_runtime.h>

// Polar encoder: N=1024, K=512, BATCH=65536.
// Bit-packed butterfly: 32 uint32 words per row; one wave handles 2 rows
// (lanes 0-31 = row A words, lanes 32-63 = row B words), 4 row-pairs per wave.
// Two-phase pack: batch all 32 predicated loads (deep vmcnt pipeline),
// then 32 branch-free ballots. Frozen words load with exec=0 (no traffic).

#define PN     1024
#define PK     512
#define PBATCH 65536
#define WORDS  32         // PN/32
#define ROWS_PER_BLOCK 32 // 4 waves x 2 rows x 4 pairs
#define PAIRS_PER_WAVE 4

__global__ __launch_bounds__(256) void polar_encode_kernel(
    const float* __restrict__ u,
    const int*   __restrict__ info_pos,
    float*       __restrict__ out)
{
    // --- inverse scatter map (codeword pos -> info index, -1 if frozen)
    __shared__ int inv[PN];
    const int tid = threadIdx.x;
    #pragma unroll
    for (int i = tid; i < PN; i += 256) inv[i] = -1;
    __syncthreads();
    #pragma unroll
    for (int k = tid; k < PK; k += 256) inv[info_pos[k]] = k;
    __syncthreads();

    const int lane = tid & 63;
    const int wave = tid >> 6;
    const int l31  = lane & 31;
    const int half = lane >> 5;              // 0 = row A, 1 = row B
    float4* out4 = (float4*)out;

    #pragma unroll
    for (int it = 0; it < PAIRS_PER_WAVE; ++it) {
        const long rA = (long)blockIdx.x * ROWS_PER_BLOCK + it * 8 + wave * 2;
        const float* urow = u + (rA + half) * (long)PK;

        // --- phase 1: batch all predicated gathers (independent, pipelined)
        float v[WORDS];
        #pragma unroll
        for (int c = 0; c < WORDS; ++c) {
            const int iv = inv[c * 32 + l31];
            v[c] = (iv >= 0) ? urow[iv] : 0.0f;
        }

        // --- phase 2: 32 branch-free ballots -> packed word per lane
        unsigned int word = 0;
        #pragma unroll
        for (int c = 0; c < WORDS; ++c) {
            const unsigned long long m = __ballot(v[c] != 0.0f);
            const unsigned int sel =
                half ? (unsigned int)(m >> 32) : (unsigned int)m;
            word = (l31 == c) ? sel : word;
        }

        // --- butterfly stages 0..4: bit distance 1,2,4,8,16 (in-word)
        word ^= (word >> 1)  & 0x55555555u;
        word ^= (word >> 2)  & 0x33333333u;
        word ^= (word >> 4)  & 0x0F0F0F0Fu;
        word ^= (word >> 8)  & 0x00FF00FFu;
        word ^= (word >> 16) & 0x0000FFFFu;

        // --- butterfly stages 5..9: word distance 1,2,4,8,16 (cross-lane;
        // off<=16 so lane^off stays within the 32-lane row half)
        #pragma unroll
        for (int off = 1; off <= 16; off <<= 1) {
            const unsigned int partner =
                (unsigned int)__shfl_xor((int)word, off, 64);
            if ((l31 & off) == 0) word ^= partner;
        }

        // --- coalesced float4 store (1 KiB per wave per instruction)
        const long base = rA * (PN / 4);
        #pragma unroll
        for (int j = 0; j < 8; ++j) {
            const int f   = j * 64 + lane;      // float4 index in the 2-row pair
            const int r   = f >> 8;             // row within pair
            const int wir = (f & 255) >> 3;     // word index within row
            const int src = wir + (r << 5);     // lane holding that word
            const unsigned int b   = (unsigned int)__shfl((int)word, src, 64);
            const unsigned int nib = (b >> ((lane & 7) * 4)) & 0xFu;
            float4 v4;
            v4.x = (nib & 1u) ? 1.0f : 0.0f;
            v4.y = (nib & 2u) ? 1.0f : 0.0f;
            v4.z = (nib & 4u) ? 1.0f : 0.0f;
            v4.w = (nib & 8u) ? 1.0f : 0.0f;
            out4[base + f] = v4;
        }
    }
}

extern "C" void kernel_launch(void* const* d_in, const int* in_sizes, int n_in,
                              void* d_out, int out_size, void* d_ws, size_t ws_size,
                              hipStream_t stream) {
    const float* u        = (const float*)d_in[0];
    const int*   info_pos = (const int*)d_in[1];
    // d_in[2] = ind_gather — unused; butterfly structure is compiled in.
    float* out = (float*)d_out;

    const int blocks = PBATCH / ROWS_PER_BLOCK;  // 2048
    polar_encode_kernel<<<blocks, 256, 0, stream>>>(u, info_pos, out);
}

// Round 4
// 359.357 us; speedup vs baseline: 1.1646x; 1.1646x over previous
//
#include <hip/hip_runtime.h>

// Polar encoder: N=1024, K=512, BATCH=65536.
// Bit-packed butterfly: 32 uint32 words per row; one wave handles 2 rows
// (lanes 0-31 = row A words, lanes 32-63 = row B words), 1 pair per wave,
// 8192 blocks (R1 shape — best measured).
// Gather path: wave-private LDS staging of u (4 coalesced dwordx4 loads per
// lane), then branch-free LDS gather + ballot pack. No exec-mask juggling.

#define PN     1024
#define PK     512
#define PBATCH 65536
#define WORDS  32   // PN/32

__global__ __launch_bounds__(256) void polar_encode_kernel(
    const float* __restrict__ u,
    const int*   __restrict__ info_pos,
    float*       __restrict__ out)
{
    // --- inverse scatter map (codeword pos -> info index, -1 if frozen)
    __shared__ int   inv[PN];
    __shared__ float su[4][2 * PK];   // per-wave staging: 2 rows of u (4 KB/wave)
    const int tid = threadIdx.x;
    #pragma unroll
    for (int i = tid; i < PN; i += 256) inv[i] = -1;
    __syncthreads();
    #pragma unroll
    for (int k = tid; k < PK; k += 256) inv[info_pos[k]] = k;
    __syncthreads();

    const int lane = tid & 63;
    const int wave = tid >> 6;
    const int l31  = lane & 31;
    const int half = lane >> 5;                    // 0 = row A, 1 = row B
    const unsigned rA = blockIdx.x * 8u + wave * 2u;

    // --- stage this wave's 2 rows of u into LDS: 256 float4 = 4 coalesced
    // dwordx4 per lane. Wave-private: no __syncthreads needed; compiler
    // inserts the vmcnt/lgkmcnt waits for the write->read dependency.
    {
        const float4* u4  = (const float4*)(u + (size_t)rA * PK);
        float4*       su4 = (float4*)su[wave];
        #pragma unroll
        for (int j = 0; j < 4; ++j)
            su4[j * 64 + lane] = u4[j * 64 + lane];
    }

    // --- gather + pack: round c builds codeword word c of both rows via
    // ballot. Branch-free: clamp address, mask bit by (iv>=0).
    const float* srow = su[wave] + half * PK;
    unsigned int word = 0;
    #pragma unroll
    for (int c = 0; c < WORDS; ++c) {
        const int   iv  = inv[c * 32 + l31];
        const float v   = srow[iv & (PK - 1)];     // always-valid address
        const bool  bit = (iv >= 0) && (v != 0.0f);
        const unsigned long long m = __ballot(bit);
        const unsigned int sel =
            half ? (unsigned int)(m >> 32) : (unsigned int)m;
        if (l31 == c) word = sel;
    }

    // --- butterfly stages 0..4: bit distance 1,2,4,8,16 (in-word)
    word ^= (word >> 1)  & 0x55555555u;
    word ^= (word >> 2)  & 0x33333333u;
    word ^= (word >> 4)  & 0x0F0F0F0Fu;
    word ^= (word >> 8)  & 0x00FF00FFu;
    word ^= (word >> 16) & 0x0000FFFFu;

    // --- butterfly stages 5..9: word distance 1,2,4,8,16 (cross-lane;
    // off<=16 so lane^off stays within the 32-lane row half)
    #pragma unroll
    for (int off = 1; off <= 16; off <<= 1) {
        const unsigned int partner =
            (unsigned int)__shfl_xor((int)word, off, 64);
        if ((l31 & off) == 0) word ^= partner;
    }

    // --- coalesced float4 store (1 KiB per wave per instruction)
    float4* out4 = (float4*)out;
    const unsigned base = rA * (PN / 4);   // rA * 256, fits 32-bit
    #pragma unroll
    for (int j = 0; j < 8; ++j) {
        const int f   = j * 64 + lane;      // float4 index in the 2-row pair
        const int r   = f >> 8;             // row within pair
        const int wir = (f & 255) >> 3;     // word index within row
        const int src = wir + (r << 5);     // lane holding that word
        const unsigned int b   = (unsigned int)__shfl((int)word, src, 64);
        const unsigned int nib = (b >> ((lane & 7) * 4)) & 0xFu;
        float4 v4;
        v4.x = (nib & 1u) ? 1.0f : 0.0f;
        v4.y = (nib & 2u) ? 1.0f : 0.0f;
        v4.z = (nib & 4u) ? 1.0f : 0.0f;
        v4.w = (nib & 8u) ? 1.0f : 0.0f;
        out4[base + f] = v4;
    }
}

extern "C" void kernel_launch(void* const* d_in, const int* in_sizes, int n_in,
                              void* d_out, int out_size, void* d_ws, size_t ws_size,
                              hipStream_t stream) {
    const float* u        = (const float*)d_in[0];
    const int*   info_pos = (const int*)d_in[1];
    // d_in[2] = ind_gather — unused; butterfly structure is compiled in.
    float* out = (float*)d_out;

    const int blocks = PBATCH / 8;  // 8 rows per block (4 waves x 2 rows)
    polar_encode_kernel<<<blocks, 256, 0, stream>>>(u, info_pos, out);
}